// Round 1
// 827.021 us; speedup vs baseline: 1.1752x; 1.1752x over previous
//
#include <hip/hip_runtime.h>

typedef short short8 __attribute__((ext_vector_type(8)));
typedef float floatx4 __attribute__((ext_vector_type(4)));
typedef unsigned short ushort8v __attribute__((ext_vector_type(8)));

#define B_ 8
#define S_ 1024
#define H_ 1024
#define NH_ 16
#define HD_ 64

__device__ __forceinline__ unsigned short f2bf(float f) {
  unsigned u = __float_as_uint(f);
  u += 0x7fffu + ((u >> 16) & 1u);   // RNE to bf16
  return (unsigned short)(u >> 16);
}

__device__ __forceinline__ floatx4 mfma16(short8 a, short8 b, floatx4 c) {
  return __builtin_amdgcn_mfma_f32_16x16x32_bf16(a, b, c, 0, 0, 0);
}

// async global -> LDS, 16B per lane. LDS dest must be waveBase + lane*16.
__device__ __forceinline__ void gload16(const void* g, void* lds) {
  __builtin_amdgcn_global_load_lds(
      (const __attribute__((address_space(1))) unsigned int*)g,
      (__attribute__((address_space(3))) unsigned int*)lds, 16, 0, 0);
}

// ---------------- convert fp32 -> bf16 (x: no perturbation) -----------------
__global__ void __launch_bounds__(256) cvt_x(const float* __restrict__ src,
                                             unsigned short* __restrict__ dst) {
  int i = (blockIdx.x * 256 + threadIdx.x) * 4;
  float4 v = *(const float4*)(src + i);
  ushort4 o;
  o.x = f2bf(v.x); o.y = f2bf(v.y); o.z = f2bf(v.z); o.w = f2bf(v.w);
  *(ushort4*)(dst + i) = o;
}

// fused weight convert; y==3 (Wo) gets w + g*relu(w)
__global__ void __launch_bounds__(256) cvt_w(
    const float* __restrict__ W0, const float* __restrict__ W1,
    const float* __restrict__ W2, const float* __restrict__ W3,
    unsigned short* __restrict__ o0, unsigned short* __restrict__ o1,
    unsigned short* __restrict__ o2, unsigned short* __restrict__ o3,
    const float* __restrict__ gLN) {
  const int which = blockIdx.y;
  const float* src = (which == 0) ? W0 : (which == 1) ? W1 : (which == 2) ? W2 : W3;
  unsigned short* dst = (which == 0) ? o0 : (which == 1) ? o1 : (which == 2) ? o2 : o3;
  const float g = (which == 3) ? gLN[0] : 0.0f;
  int i = (blockIdx.x * 256 + threadIdx.x) * 4;
  float4 v = *(const float4*)(src + i);
  ushort4 o;
  o.x = f2bf(v.x + g * fmaxf(v.x, 0.f));
  o.y = f2bf(v.y + g * fmaxf(v.y, 0.f));
  o.z = f2bf(v.z + g * fmaxf(v.z, 0.f));
  o.w = f2bf(v.w + g * fmaxf(v.w, 0.f));
  *(ushort4*)(dst + i) = o;
}

// ---------------- shared GEMM mainloop: C(128x128) = A[M,K] * B^T  (bf16) ----
// As/Bs: [128][32] bf16, linear. Staged via global_load_lds (m97 pattern).
// 256 threads, 4 waves each computing 64x64.
__device__ __forceinline__ void gemm_mainloop(const unsigned short* __restrict__ Ag,
                                              const unsigned short* __restrict__ Bg,
                                              int K,
                                              unsigned short* As, unsigned short* Bs,
                                              floatx4 acc[4][4]) {
  const int tid = threadIdx.x;
  const int l = tid & 63, w = tid >> 6;
  const int l15 = l & 15, l4 = l >> 4;
  const int wm = (w & 1) << 6, wn = (w >> 1) << 6;
  // staging: wave w owns chunks 2w,2w+1 (1KB each) of both tiles.
  // lane l -> row = w*32 + l/4 (+16), colElem = (l&3)*8 ; LDS byte = w*2048 + l*16 (+1024)
  const int srow = w * 32 + (l >> 2);
  const int scol = (l & 3) << 3;
  for (int k0 = 0; k0 < K; k0 += 32) {
    __syncthreads();
    gload16(&Ag[(size_t)srow * K + k0 + scol],        &As[srow * 32 + scol]);
    gload16(&Ag[(size_t)(srow + 16) * K + k0 + scol], &As[(srow + 16) * 32 + scol]);
    gload16(&Bg[(size_t)srow * K + k0 + scol],        &Bs[srow * 32 + scol]);
    gload16(&Bg[(size_t)(srow + 16) * K + k0 + scol], &Bs[(srow + 16) * 32 + scol]);
    __syncthreads();
    short8 a[4], bb[4];
#pragma unroll
    for (int i = 0; i < 4; ++i)
      a[i] = *(const short8*)&As[(wm + i * 16 + l15) * 32 + l4 * 8];
#pragma unroll
    for (int j = 0; j < 4; ++j)
      bb[j] = *(const short8*)&Bs[(wn + j * 16 + l15) * 32 + l4 * 8];
#pragma unroll
    for (int i = 0; i < 4; ++i)
#pragma unroll
      for (int j = 0; j < 4; ++j)
        acc[i][j] = mfma16(a[i], bb[j], acc[i][j]);
  }
}

// ---------------- QKV: q/k/v = x @ W^T + b, bf16 out [8192,1024] -------------
__global__ void __launch_bounds__(256) gemm_qkv(
    const unsigned short* __restrict__ xb,
    const unsigned short* __restrict__ wq, const unsigned short* __restrict__ wk,
    const unsigned short* __restrict__ wv,
    const float* __restrict__ bq, const float* __restrict__ bk, const float* __restrict__ bv,
    unsigned short* __restrict__ oq, unsigned short* __restrict__ ok,
    unsigned short* __restrict__ ov) {
  __shared__ __align__(16) unsigned short As[128 * 32];
  __shared__ __align__(16) unsigned short Bs[128 * 32];
  const int z = blockIdx.z;
  const unsigned short* W = (z == 0) ? wq : (z == 1) ? wk : wv;
  const float* bias        = (z == 0) ? bq : (z == 1) ? bk : bv;
  unsigned short* O        = (z == 0) ? oq : (z == 1) ? ok : ov;
  const int nBase = blockIdx.x * 128, mBase = blockIdx.y * 128;
  floatx4 acc[4][4];
  const floatx4 fz = {0.f, 0.f, 0.f, 0.f};
#pragma unroll
  for (int i = 0; i < 4; ++i)
#pragma unroll
    for (int j = 0; j < 4; ++j) acc[i][j] = fz;
  gemm_mainloop(xb + (size_t)mBase * H_, W + (size_t)nBase * H_, H_, As, Bs, acc);
  const int l = threadIdx.x & 63, w = threadIdx.x >> 6;
  const int l15 = l & 15, l4 = l >> 4;
  const int wm = (w & 1) << 6, wn = (w >> 1) << 6;
#pragma unroll
  for (int i = 0; i < 4; ++i) {
    int row = mBase + wm + i * 16 + l4 * 4;
#pragma unroll
    for (int j = 0; j < 4; ++j) {
      int col = nBase + wn + j * 16 + l15;
      float bcol = bias[col];
#pragma unroll
      for (int r = 0; r < 4; ++r)
        O[(size_t)(row + r) * H_ + col] = f2bf(acc[i][j][r] + bcol);
    }
  }
}

// ---------------- V transpose: [B*S, NH*HD] -> [B,NH,HD,S] -------------------
__global__ void __launch_bounds__(256) transpose_v(const unsigned short* __restrict__ vb,
                                                   unsigned short* __restrict__ vt) {
  const int st = blockIdx.x, h = blockIdx.y, b = blockIdx.z;
  __shared__ __align__(16) unsigned short t[64 * 72];  // pad 8 -> 144B rows
  const int tid = threadIdx.x;
  const unsigned short* src = vb + (size_t)(b * S_ + st * 64) * H_ + h * HD_;
  for (int c = tid; c < 512; c += 256) {
    int i = c >> 3, dg = (c & 7) << 3;
    *(uint4*)&t[i * 72 + dg] = *(const uint4*)&src[(size_t)i * H_ + dg];
  }
  __syncthreads();
  unsigned short* dst = vt + ((size_t)(b * NH_ + h) * HD_) * S_ + st * 64;
  for (int c = tid; c < 512; c += 256) {
    int d = c >> 3, ig = (c & 7) << 3;
    ushort8v v;
#pragma unroll
    for (int ii = 0; ii < 8; ++ii) v[ii] = t[(ig + ii) * 72 + d];
    *(ushort8v*)&dst[(size_t)d * S_ + ig] = v;
  }
}

// ---------------- attention: probs (fp32) + ctx (bf16) ----------------------
// block = (qt, h, b): 64 q-rows. 4 waves x 16 rows. BK=128.
// Ks swizzle: 8 slots/row (16B), slot' = slot ^ (row&7).
// Vts/Ps swizzle: 16 slots/row, slot' = slot ^ (row&15).
// All staged via global_load_lds with pre-swizzled global source (linear LDS dest).
__global__ void __launch_bounds__(256) attn_kernel(
    const unsigned short* __restrict__ qg_, const unsigned short* __restrict__ kg_,
    const unsigned short* __restrict__ vtg_,
    float* __restrict__ probs, unsigned short* __restrict__ ctxb) {
  const int qt = blockIdx.x, h = blockIdx.y, b = blockIdx.z;
  __shared__ __align__(16) unsigned short Qs[64 * 64];
  __shared__ __align__(16) unsigned short Ks[128 * 64];
  __shared__ __align__(16) unsigned short Vts[64 * 128];
  __shared__ __align__(16) unsigned short Ps[64 * 128];
  const int tid = threadIdx.x;
  const int l = tid & 63, w = tid >> 6;
  const int l15 = l & 15, l4 = l >> 4;
  const int l7 = l & 7, lr8 = l >> 3;          // lr8 = row-within-1KB-chunk (K-style)

  const unsigned short* qg = qg_ + ((size_t)(b * S_) + qt * 64) * H_ + h * HD_;
  const unsigned short* kg = kg_ + (size_t)(b * S_) * H_ + h * HD_;
  const unsigned short* vg = vtg_ + ((size_t)(b * NH_ + h) * HD_) * S_;

  // pre-swizzled source column (elements) for K staging: ((l&7) ^ (row&7))*8,
  // row&7 == l>>3 because chunks are 8-row aligned.
  const int kcol = (l7 ^ lr8) << 3;

  // ---- stage Q 64x64, linear (read once; conflicts negligible) ----
#pragma unroll
  for (int c = 0; c < 2; ++c) {
    int row = w * 16 + c * 8 + lr8;
    gload16(&qg[(size_t)row * H_ + (l7 << 3)], &Qs[row * 64 + (l7 << 3)]);
  }
  __syncthreads();
  short8 aq0 = *(const short8*)&Qs[(w * 16 + l15) * 64 + l4 * 8];
  short8 aq1 = *(const short8*)&Qs[(w * 16 + l15) * 64 + 32 + l4 * 8];

  // -------- pass 1: row sums of exp(scores); no max-sub (|s| <~ 25) --------
  float esum[4] = {0.f, 0.f, 0.f, 0.f};
  for (int kt = 0; kt < 8; ++kt) {
    __syncthreads();
#pragma unroll
    for (int c = 0; c < 4; ++c) {                 // K tile 128x64, swizzled source
      int row = w * 32 + c * 8 + lr8;
      gload16(&kg[(size_t)(kt * 128 + row) * H_ + kcol], &Ks[row * 64 + (l7 << 3)]);
    }
    __syncthreads();
#pragma unroll
    for (int j = 0; j < 8; ++j) {
      int rr = l15 & 7;
      short8 b0 = *(const short8*)&Ks[(j * 16 + l15) * 64 + ((l4 ^ rr) << 3)];
      short8 b1 = *(const short8*)&Ks[(j * 16 + l15) * 64 + (((4 + l4) ^ rr) << 3)];
      floatx4 s = {0.f, 0.f, 0.f, 0.f};
      s = mfma16(aq0, b0, s);
      s = mfma16(aq1, b1, s);
#pragma unroll
      for (int r = 0; r < 4; ++r) esum[r] += __expf(s[r]);
    }
  }
#pragma unroll
  for (int m = 1; m < 16; m <<= 1)
#pragma unroll
    for (int r = 0; r < 4; ++r) esum[r] += __shfl_xor(esum[r], m, 64);
  float rinv[4];
#pragma unroll
  for (int r = 0; r < 4; ++r) rinv[r] = 1.0f / esum[r];

  // -------- pass 2: probs write + PV accumulate ----------------------------
  const floatx4 fz = {0.f, 0.f, 0.f, 0.f};
  floatx4 cacc[4];
#pragma unroll
  for (int dt = 0; dt < 4; ++dt) cacc[dt] = fz;
  const int qrow_base = qt * 64 + w * 16 + l4 * 4;
  for (int kt = 0; kt < 8; ++kt) {
    __syncthreads();
#pragma unroll
    for (int c = 0; c < 4; ++c) {                 // K tile, swizzled source
      int row = w * 32 + c * 8 + lr8;
      gload16(&kg[(size_t)(kt * 128 + row) * H_ + kcol], &Ks[row * 64 + (l7 << 3)]);
    }
#pragma unroll
    for (int c = 0; c < 4; ++c) {                 // V^T tile 64x128, swizzled source
      int row = w * 16 + c * 4 + l4;              // row&15 = c*4 + l4
      int scol = (l15 ^ (c * 4 + l4)) << 3;
      gload16(&vg[(size_t)row * S_ + kt * 128 + scol], &Vts[row * 128 + (l15 << 3)]);
    }
    __syncthreads();
#pragma unroll
    for (int j = 0; j < 8; ++j) {
      int rr = l15 & 7;
      short8 b0 = *(const short8*)&Ks[(j * 16 + l15) * 64 + ((l4 ^ rr) << 3)];
      short8 b1 = *(const short8*)&Ks[(j * 16 + l15) * 64 + (((4 + l4) ^ rr) << 3)];
      floatx4 s = {0.f, 0.f, 0.f, 0.f};
      s = mfma16(aq0, b0, s);
      s = mfma16(aq1, b1, s);
      float* pp = probs + ((size_t)((b * NH_ + h) * S_) + qrow_base) * S_ + kt * 128 + j * 16 + l15;
#pragma unroll
      for (int r = 0; r < 4; ++r) {
        float p = __expf(s[r]) * rinv[r];
        pp[(size_t)r * S_] = p;
        int prow = w * 16 + l4 * 4 + r;           // row&15 = l4*4 + r
        int pslot = (j * 2 + (l15 >> 3)) ^ (l4 * 4 + r);
        Ps[prow * 128 + (pslot << 3) + (l15 & 7)] = f2bf(p);
      }
    }
    __syncthreads();
    short8 ap[4];
#pragma unroll
    for (int ks = 0; ks < 4; ++ks)
      ap[ks] = *(const short8*)&Ps[(w * 16 + l15) * 128 + (((ks * 4 + l4) ^ l15) << 3)];
#pragma unroll
    for (int dt = 0; dt < 4; ++dt)
#pragma unroll
      for (int ks = 0; ks < 4; ++ks) {
        short8 bv = *(const short8*)&Vts[(dt * 16 + l15) * 128 + (((ks * 4 + l4) ^ l15) << 3)];
        cacc[dt] = mfma16(ap[ks], bv, cacc[dt]);
      }
  }
  const int rowg = b * S_ + qt * 64 + w * 16 + l4 * 4;
#pragma unroll
  for (int dt = 0; dt < 4; ++dt)
#pragma unroll
    for (int r = 0; r < 4; ++r)
      ctxb[(size_t)(rowg + r) * H_ + h * HD_ + dt * 16 + l15] = f2bf(cacc[dt][r]);
}

// ---------------- out-proj: h = ctx @ p(Wo)^T + p(bo) + x (fp32) ------------
__global__ void __launch_bounds__(256) gemm_out(
    const unsigned short* __restrict__ ctxb, const unsigned short* __restrict__ wob,
    const float* __restrict__ bo, const float* __restrict__ gln,
    const float* __restrict__ xres, float* __restrict__ hres) {
  __shared__ __align__(16) unsigned short As[128 * 32];
  __shared__ __align__(16) unsigned short Bs[128 * 32];
  const int nBase = blockIdx.x * 128, mBase = blockIdx.y * 128;
  floatx4 acc[4][4];
  const floatx4 fz = {0.f, 0.f, 0.f, 0.f};
#pragma unroll
  for (int i = 0; i < 4; ++i)
#pragma unroll
    for (int j = 0; j < 4; ++j) acc[i][j] = fz;
  gemm_mainloop(ctxb + (size_t)mBase * H_, wob + (size_t)nBase * H_, H_, As, Bs, acc);
  const float g = gln[0];
  const int l = threadIdx.x & 63, w = threadIdx.x >> 6;
  const int l15 = l & 15, l4 = l >> 4;
  const int wm = (w & 1) << 6, wn = (w >> 1) << 6;
#pragma unroll
  for (int i = 0; i < 4; ++i) {
    int row = mBase + wm + i * 16 + l4 * 4;
#pragma unroll
    for (int j = 0; j < 4; ++j) {
      int col = nBase + wn + j * 16 + l15;
      float pb = bo[col];
      pb += g * fmaxf(pb, 0.f);
#pragma unroll
      for (int r = 0; r < 4; ++r)
        hres[(size_t)(row + r) * H_ + col] =
            acc[i][j][r] + pb + xres[(size_t)(row + r) * H_ + col];
    }
  }
}

// ---------------- LayerNorm (no weight/bias), biased var, eps=1e-12 ---------
__global__ void __launch_bounds__(256) ln_kernel(const float* __restrict__ hres,
                                                 float* __restrict__ out) {
  const int row = blockIdx.x;
  const int tid = threadIdx.x;
  const float* xr = hres + (size_t)row * H_;
  float4 v = *(const float4*)&xr[tid * 4];
  float s = v.x + v.y + v.z + v.w;
  float q = v.x * v.x + v.y * v.y + v.z * v.z + v.w * v.w;
#pragma unroll
  for (int m = 1; m < 64; m <<= 1) {
    s += __shfl_xor(s, m, 64);
    q += __shfl_xor(q, m, 64);
  }
  __shared__ float sh[8];
  const int w = tid >> 6, l = tid & 63;
  if (l == 0) { sh[w] = s; sh[4 + w] = q; }
  __syncthreads();
  s = sh[0] + sh[1] + sh[2] + sh[3];
  q = sh[4] + sh[5] + sh[6] + sh[7];
  float mean = s * (1.f / 1024.f);
  float var = q * (1.f / 1024.f) - mean * mean;
  float inv = rsqrtf(var + 1e-12f);
  float4 o;
  o.x = (v.x - mean) * inv;
  o.y = (v.y - mean) * inv;
  o.z = (v.z - mean) * inv;
  o.w = (v.w - mean) * inv;
  *(float4*)&out[(size_t)row * H_ + tid * 4] = o;
}

extern "C" void kernel_launch(void* const* d_in, const int* in_sizes, int n_in,
                              void* d_out, int out_size, void* d_ws, size_t ws_size,
                              hipStream_t stream) {
  const float* x   = (const float*)d_in[0];
  const float* Wq  = (const float*)d_in[1];
  const float* bq  = (const float*)d_in[2];
  const float* Wk  = (const float*)d_in[3];
  const float* bk  = (const float*)d_in[4];
  const float* Wv  = (const float*)d_in[5];
  const float* bv  = (const float*)d_in[6];
  const float* Wo  = (const float*)d_in[7];
  const float* bo  = (const float*)d_in[8];
  const float* gLN = (const float*)d_in[10];

  float* out   = (float*)d_out;
  float* probs = out + (size_t)B_ * S_ * H_;  // 8388608 floats of LN output first

  // workspace layout (bf16 elements); ctx aliases xb, hres aliases qb+kb
  unsigned short* xb  = (unsigned short*)d_ws;
  unsigned short* wqb = xb + 8388608;
  unsigned short* wkb = wqb + 1048576;
  unsigned short* wvb = wkb + 1048576;
  unsigned short* wob = wvb + 1048576;
  unsigned short* qb  = wob + 1048576;
  unsigned short* kb  = qb + 8388608;
  unsigned short* vb  = kb + 8388608;
  unsigned short* vt  = vb + 8388608;
  unsigned short* ctxb = xb;        // xb dead after gemm_qkv
  float* hres = (float*)qb;         // qb/kb dead after attn

  cvt_x<<<8192, 256, 0, stream>>>(x, xb);
  cvt_w<<<dim3(1024, 4), 256, 0, stream>>>(Wq, Wk, Wv, Wo, wqb, wkb, wvb, wob, gLN);

  gemm_qkv<<<dim3(8, 64, 3), 256, 0, stream>>>(xb, wqb, wkb, wvb, bq, bk, bv, qb, kb, vb);
  transpose_v<<<dim3(16, 16, 8), 256, 0, stream>>>(vb, vt);
  attn_kernel<<<dim3(16, 16, 8), 256, 0, stream>>>(qb, kb, vt, probs, ctxb);
  gemm_out<<<dim3(8, 64, 1), 256, 0, stream>>>(ctxb, wob, bo, gLN, x, hres);
  ln_kernel<<<8192, 256, 0, stream>>>(hres, out);
}